// Round 1
// baseline (109.101 us; speedup 1.0000x reference)
//
#include <hip/hip_runtime.h>
#include <stdint.h>

#define N_PTS 256

typedef unsigned long long ull;
typedef float    v2f __attribute__((ext_vector_type(2)));
typedef unsigned v2u __attribute__((ext_vector_type(2)));

// Single-inst DPP mov (old=0, bound_ctrl=1); row_ror rotates within 16-lane
// rows, no invalid lanes -> the 0 never appears.
template<int CTRL>
__device__ __forceinline__ int dppmov(int x) {
    return __builtin_amdgcn_update_dpp(0, x, CTRL, 0xF, 0xF, true);
}

// All-lane MAX of f64 keys WITHIN each 16-lane row (4 rows share the stages).
__device__ __forceinline__ double rowmax16(double x) {
    #define STAGE(C) { \
        ull u = __double_as_longlong(x); \
        int lo = dppmov<C>((int)(unsigned)u); \
        int hi = dppmov<C>((int)(unsigned)(u >> 32)); \
        double r = __longlong_as_double(((ull)(unsigned)hi << 32) | (unsigned)lo); \
        x = fmax(x, r); }
    STAGE(0x121)  // row_ror:1
    STAGE(0x122)  // row_ror:2
    STAGE(0x124)  // row_ror:4
    STAGE(0x128)  // row_ror:8
    #undef STAGE
    return x;
}

// Exact (dist, index) argmin via f64 MAX over keys:
//   hi = (used_s << 31) | (0x7F000000 - du)   [3 VALU: lshl, sub, and_or]
//   lo = 255 - k  -- loop-invariant, PINNED in the .x half of a persistent
//   VGPR pair (kp[s]); each step only redefines the .y subreg, so no per-step
//   v_movs to assemble the f64 operand.
// 0x7F000000 - du: exact, strictly order-reversing, exponent < 0x7FF for all
// real du (N(0,1) data -> du << 0x7F000000) => positive double, no NaN.
// used slots: sign bit set -> negative double -> always lose fmax.
// hi-tie -> larger lo wins = smaller k = reference's first-min-wins. Bit-exact.
__device__ __forceinline__ void reduce16(const float (&d)[16], unsigned used,
                                         v2u (&kp)[16],
                                         unsigned& kk, unsigned& mu) {
    const unsigned SGN = 0x80000000u, KH = 0x7F000000u;
    #pragma unroll
    for (int s = 0; s < 16; ++s) {
        unsigned du = __float_as_uint(d[s]);
        unsigned t  = used << (31 - s);          // bit s -> sign position
        kp[s].y = (t & SGN) | (KH - du);         // def of odd subreg only
    }
    double kd[8];
    #pragma unroll
    for (int s = 0; s < 8; ++s) {
        double a = __builtin_bit_cast(double, kp[s]);
        double b = __builtin_bit_cast(double, kp[s + 8]);
        kd[s] = fmax(a, b);
    }
    #pragma unroll
    for (int s = 0; s < 4; ++s) kd[s] = fmax(kd[s], kd[s + 4]);
    kd[0] = fmax(kd[0], kd[2]);
    kd[1] = fmax(kd[1], kd[3]);
    double km = rowmax16(fmax(kd[0], kd[1]));
    ull u = __double_as_longlong(km);
    kk = 255u - (unsigned)u;                     // lo = 255-k  ->  k
    mu = KH - (unsigned)(u >> 32);               // hi -> exact dist bits
}

__device__ __forceinline__ void finalize(unsigned kk, unsigned mu,
                                         unsigned& k, float& se) {
    const unsigned BIG_U = 0x47810200u;  // bits of 66049.0f = 257^2
    k  = (mu < BIG_U) ? kk : 0u;
    se = __uint_as_float(mu < BIG_U ? mu : BIG_U);
}

__device__ __forceinline__ void claim(unsigned sk, unsigned rl16, unsigned& used) {
    unsigned sbit = 1u << (sk >> 4);
    used |= (rl16 == (sk & 15u)) ? sbit : 0u;
}

// Distance prep for one target group, guaranteed packed-fp32 (VOP3P).
// Exactness: q' = p - t = -(t - p) exactly; q'*q' = q*q exactly; pk halves
// round identically to scalar v_add/v_mul -> bit-exact with reference.
// 5 pk instrs per 2 slots (+2 negs, +2 dup pairs) vs 5 scalar instrs per slot.
__device__ __forceinline__ void prep16(const v2f t,
                                       const v2f (&pX)[8], const v2f (&pY)[8],
                                       float (&d)[16]) {
    float ntx = -t.x, nty = -t.y;
    v2f txx = {ntx, ntx};
    v2f tyy = {nty, nty};
    #pragma unroll
    for (int i = 0; i < 8; ++i) {
        v2f qx, qy, sx, sy, dd;
        asm("v_pk_add_f32 %0, %1, %2" : "=v"(qx) : "v"(pX[i]), "v"(txx));
        asm("v_pk_add_f32 %0, %1, %2" : "=v"(qy) : "v"(pY[i]), "v"(tyy));
        asm("v_pk_mul_f32 %0, %1, %1" : "=v"(sx) : "v"(qx));
        asm("v_pk_mul_f32 %0, %1, %1" : "=v"(sy) : "v"(qy));
        asm("v_pk_add_f32 %0, %1, %2" : "=v"(dd) : "v"(sx), "v"(sy));
        d[2 * i]     = dd.x;
        d[2 * i + 1] = dd.y;
    }
}

// One wave per batch; wave = 4 rows x 16 lanes; each row = replicated
// candidate set (16 slots/lane, k = slot*16 + rl); 4 targets/group
// speculatively. Collision handling moved behind ONE uniform branch so the
// common (no-collision) path is two big scheduling regions: the machine
// scheduler can sink the pk-prep + next key-build into the f64-tree and
// readlane latency shadows (it cannot move VALU across s_cbranch regions,
// which is what capped VALUBusy at 61% with the 3-branch version).
__global__ __launch_bounds__(256, 2) void greedy_match_kernel(
    const float* __restrict__ input,
    const float* __restrict__ targets,
    float* __restrict__ out,
    int B, float scale)
{
    __shared__ v2f   tl[4][N_PTS];
    __shared__ float wsum[4];

    const unsigned lane = threadIdx.x & 63;
    const int      wid  = threadIdx.x >> 6;
    const int      b    = blockIdx.x * 4 + wid;
    const bool     vB   = (b < B);
    const int      cb   = vB ? b : 0;

    const unsigned rl16 = lane & 15u;
    const unsigned rowv = lane >> 4;

    const v2f* pin = (const v2f*)(input   + (size_t)cb * (2 * N_PTS));
    const v2f* ptg = (const v2f*)(targets + (size_t)cb * (2 * N_PTS));

    #pragma unroll
    for (int c = 0; c < 4; ++c) {
        int idx = c * 64 + (int)lane;
        tl[wid][idx] = ptg[idx];
    }
    __syncthreads();
    const v2f* tlw = tl[wid];

    // SoA repack: pX[i] = x of slots (2i, 2i+1), pY[i] = y -- feeds VOP3P.
    v2f pX[8], pY[8];
    #pragma unroll
    for (int i = 0; i < 8; ++i) {
        v2f a = pin[((2 * i)     << 4) + rl16];
        v2f b2 = pin[((2 * i + 1) << 4) + rl16];
        pX[i] = {a.x, b2.x};
        pY[i] = {a.y, b2.y};
    }

    // Persistent key pairs: .x = lo tiebreak constant (255-k), pinned for the
    // whole loop; .y rewritten by each reduce16.
    v2u kp[16];
    #pragma unroll
    for (int s = 0; s < 16; ++s) {
        kp[s].x = 255u - (unsigned)((s << 4) | rl16);
        kp[s].y = 0u;
    }

    unsigned used = 0u;
    float acc = 0.0f;

    {
        #pragma clang fp contract(off)

        float dA[16], dB[16];
        prep16(tlw[rowv], pX, pY, dA);   // group 0

        #define STEP(dcur, dnext, g)                                          \
        {                                                                     \
            unsigned kk, mu, kf; float sef;                                   \
            reduce16(dcur, used, kp, kk, mu);                                 \
            finalize(kk, mu, kf, sef);                                        \
            unsigned vk = kf; float vse = sef;                                \
            unsigned k0 = (unsigned)__builtin_amdgcn_readlane((int)vk, 0);    \
            unsigned k1 = (unsigned)__builtin_amdgcn_readlane((int)vk, 16);   \
            unsigned k2 = (unsigned)__builtin_amdgcn_readlane((int)vk, 32);   \
            unsigned k3 = (unsigned)__builtin_amdgcn_readlane((int)vk, 48);   \
            bool col = (k1 == k0) | (k2 == k0) | (k2 == k1)                   \
                     | (k3 == k0) | (k3 == k1) | (k3 == k2);                  \
            if (__builtin_expect(col, 0)) {                                   \
                /* rare slow path: exact sequential resolve (R13 semantics) */\
                claim(k0, rl16, used);                                        \
                if (k1 == k0) {                                               \
                    reduce16(dcur, used, kp, kk, mu);                         \
                    finalize(kk, mu, kf, sef);                                \
                    bool upd = (rowv >= 1u);                                  \
                    vk = upd ? kf : vk; vse = upd ? sef : vse;                \
                    k1 = (unsigned)__builtin_amdgcn_readlane((int)vk, 16);    \
                    k2 = (unsigned)__builtin_amdgcn_readlane((int)vk, 32);    \
                    k3 = (unsigned)__builtin_amdgcn_readlane((int)vk, 48);    \
                }                                                             \
                claim(k1, rl16, used);                                        \
                if (k2 == k0 || k2 == k1) {                                   \
                    reduce16(dcur, used, kp, kk, mu);                         \
                    finalize(kk, mu, kf, sef);                                \
                    bool upd = (rowv >= 2u);                                  \
                    vk = upd ? kf : vk; vse = upd ? sef : vse;                \
                    k2 = (unsigned)__builtin_amdgcn_readlane((int)vk, 32);    \
                    k3 = (unsigned)__builtin_amdgcn_readlane((int)vk, 48);    \
                }                                                             \
                claim(k2, rl16, used);                                        \
                if (k3 == k0 || k3 == k1 || k3 == k2) {                       \
                    reduce16(dcur, used, kp, kk, mu);                         \
                    finalize(kk, mu, kf, sef);                                \
                    bool upd = (rowv >= 3u);                                  \
                    vk = upd ? kf : vk; vse = upd ? sef : vse;                \
                    k3 = (unsigned)__builtin_amdgcn_readlane((int)vk, 48);    \
                }                                                             \
                claim(k3, rl16, used);                                        \
            } else {                                                          \
                /* no collisions: claims commute, stay in one region */       \
                claim(k0, rl16, used);                                        \
                claim(k1, rl16, used);                                        \
                claim(k2, rl16, used);                                        \
                claim(k3, rl16, used);                                        \
            }                                                                 \
            acc += vse;                                                       \
            prep16(tlw[((((g) + 1) & 63) << 2) + rowv], pX, pY, dnext);       \
        }

        #pragma unroll 1
        for (int g = 0; g < 64; g += 2) {
            STEP(dA, dB, g)       // resolves group g,   preps dB
            STEP(dB, dA, g + 1)   // resolves group g+1, preps dA
        }
        #undef STEP
    }

    // sum 4 row-subtotals: xor16 swizzle + xor32 bpermute
    int t1 = __builtin_amdgcn_ds_swizzle(__float_as_int(acc), 0x401F);
    float a2 = acc + __int_as_float(t1);
    int t2 = __builtin_amdgcn_ds_bpermute((int)((lane ^ 32u) << 2), __float_as_int(a2));
    float tot = a2 + __int_as_float(t2);

    if (lane == 0) wsum[wid] = vB ? tot : 0.0f;
    __syncthreads();
    if (threadIdx.x == 0) {
        float s = (wsum[0] + wsum[1] + wsum[2] + wsum[3]) * scale;
        atomicAdd(out, s);
    }
}

extern "C" void kernel_launch(void* const* d_in, const int* in_sizes, int n_in,
                              void* d_out, int out_size, void* d_ws, size_t ws_size,
                              hipStream_t stream) {
    const float* input   = (const float*)d_in[0];
    const float* targets = (const float*)d_in[1];
    float* out = (float*)d_out;

    const int B = in_sizes[0] / (2 * N_PTS);
    const float scale = 1.0f / ((float)B * (float)(2 * N_PTS));

    // d_out is poisoned 0xAA before every call — zero it (graph-capturable).
    (void)hipMemsetAsync(d_out, 0, sizeof(float) * (size_t)out_size, stream);

    const int blocks = (B + 3) / 4;  // 4 waves (4 batches) per 256-thread block
    greedy_match_kernel<<<blocks, 256, 0, stream>>>(input, targets, out, B, scale);
}